// Round 5
// baseline (350.770 us; speedup 1.0000x reference)
//
#include <hip/hip_runtime.h>
#include <hip/hip_fp16.h>

#define N_NODES 100000
#define N_EDGES 1600000
#define E_TOT   (N_EDGES + N_NODES)   // 1,700,000 incl. self-loops
#define NEG_SLOPE 0.2f
#define PART_EPB 4096                 // edges per partition block
#define NBUCK ((N_NODES + 255) / 256) // 391 buckets of 256 nodes
#define PBSTRIDE 5632                 // slots/bucket: mean 4352 + 20 sigma
#define NGEMM ((N_NODES + 63) / 64)   // 1563 gemm blocks (64 rows each)
#define NPART ((E_TOT + PART_EPB - 1) / PART_EPB)   // 416 partition blocks

using f16x8 = __attribute__((ext_vector_type(8))) _Float16;
using f32x4 = __attribute__((ext_vector_type(4))) float;
union H8 { f16x8 v; _Float16 h[8]; __half2 h2[4]; };
union H4 { __half2 h2[2]; uint2 u; };

// ---------------------------------------------------------------------------
// k_prep (replaces the ibcnt memset 1-for-1): zero bcnt + precompute the
// folded attention matrices:
//   WaT1[n][k] (16x128 f16): n<4 -> sum_c W1[k][n*32+c]*a_src1[n*32+c]
//                            4<=n<8 -> same with a_dst1; n>=8 -> 0.
//   WaT2[n][k] (16x128 f16): n=0 -> sum_j W2[k][j]*a_src2[j]; n=1 -> a_dst2.
// al1 = x @ Wa1 etc. become ONE extra MFMA B-tile in the GEMMs, removing all
// epilogue cross-lane reductions (R5: 1024 ds-swizzles/block in gemm1).
// Coalesced: loop k, lane j reads W1[k][j]; reduce over 32-lane head groups.
// ---------------------------------------------------------------------------
__global__ __launch_bounds__(128)
void k_prep(const float* __restrict__ W1, const float* __restrict__ as1,
            const float* __restrict__ ad1, const float* __restrict__ W2,
            const float* __restrict__ as2, const float* __restrict__ ad2,
            _Float16* __restrict__ WaT1, _Float16* __restrict__ WaT2,
            int* __restrict__ bcnt) {
    const int t = threadIdx.x;               // 0..127
    for (int i = t; i < NBUCK; i += 128) bcnt[i] = 0;

    // WaT1: j = t (feature col of W1), head h = j>>5
    const float a1s = as1[t], a1d = ad1[t];
    for (int k = 0; k < 128; ++k) {
        const float wv = W1[(size_t)k * 128 + t];    // coalesced
        float ps = wv * a1s;
        float pd = wv * a1d;
#pragma unroll
        for (int o = 1; o < 32; o <<= 1) {           // reduce within 32-lane head group
            ps += __shfl_xor(ps, o, 32);
            pd += __shfl_xor(pd, o, 32);
        }
        if ((t & 31) == 0) {
            const int h = t >> 5;
            WaT1[h * 128 + k] = (_Float16)ps;
            WaT1[(4 + h) * 128 + k] = (_Float16)pd;
        }
    }
    for (int n = 8; n < 16; ++n) WaT1[n * 128 + t] = (_Float16)0.f;

    // WaT2: j = t&15, kb = t>>4; k = k8*8 + kb
    const int j = t & 15, kb = t >> 4;
    const float a2s = as2[j], a2d = ad2[j];
    for (int k8 = 0; k8 < 16; ++k8) {
        const int k = k8 * 8 + kb;
        const float wv = W2[(size_t)k * 16 + j];     // 64B runs
        float ps = wv * a2s;
        float pd = wv * a2d;
#pragma unroll
        for (int o = 1; o < 16; o <<= 1) {
            ps += __shfl_xor(ps, o, 16);
            pd += __shfl_xor(pd, o, 16);
        }
        if (j == 0) {
            WaT2[k] = (_Float16)ps;
            WaT2[128 + k] = (_Float16)pd;
        }
    }
    for (int n = 2; n < 16; ++n) WaT2[n * 128 + t] = (_Float16)0.f;
}

// ---------------------------------------------------------------------------
// Merged kernel: blocks < NGEMM do the layer-1 GEMM via MFMA (staged-x LDS
// tile, M=64). Blocks >= NGEMM do the edge bucket-partition (independent).
// R5: al1/ar1 come from an extra MFMA B-tile (WaT1) computed by wave 0 —
// the 1024 ds-swizzle/block epilogue reduction is GONE (stores only).
// Partition now uses 256-node buckets (NBUCK=391) for fill3 parallelism.
// ---------------------------------------------------------------------------
__global__ __launch_bounds__(256)
void k_gemm1_part(const float* __restrict__ x, const float* __restrict__ W1,
                  const _Float16* __restrict__ WaT1,
                  const int* __restrict__ ei, int* __restrict__ bcnt, int* __restrict__ pairs,
                  __half* __restrict__ xw1h, float* __restrict__ al1, float* __restrict__ ar1) {
    __shared__ int lcnt[NBUCK + 1];
    __shared__ int lbase[NBUCK + 1];
    __shared__ _Float16 sx[64][136];         // 17.4 KB; 272B row stride (2-way = free, m136)
    const int t = threadIdx.x;

    if (blockIdx.x >= NGEMM) {
        // ===== edge-partition role =====
        const int base = ((int)blockIdx.x - NGEMM) * PART_EPB;
        for (int i = t; i < NBUCK; i += 256) lcnt[i] = 0;
        __syncthreads();
        int sr[16], dr[16];
#pragma unroll
        for (int u = 0; u < 16; ++u) {
            const int e = base + u * 256 + t;    // coalesced
            if (e < E_TOT) {
                int s, d;
                if (e < N_EDGES) { s = ei[e]; d = ei[N_EDGES + e]; }
                else             { s = d = e - N_EDGES; }
                sr[u] = s; dr[u] = d;
                atomicAdd(&lcnt[d >> 8], 1);     // LDS
            } else dr[u] = -1;
        }
        __syncthreads();
        for (int i = t; i < NBUCK; i += 256) {
            const int c = lcnt[i];
            lbase[i] = (c > 0) ? atomicAdd(&bcnt[i], c) : 0;   // global, 1/bucket
            lcnt[i] = 0;
        }
        __syncthreads();
#pragma unroll
        for (int u = 0; u < 16; ++u) {
            if (dr[u] >= 0) {
                const int bk = dr[u] >> 8;
                const int r = atomicAdd(&lcnt[bk], 1);         // LDS
                pairs[(size_t)bk * PBSTRIDE + lbase[bk] + r] = (sr[u] << 8) | (dr[u] & 255);
            }
        }
        return;
    }

    // ===== MFMA GEMM role =====
    const int n0 = (int)blockIdx.x * 64;

    // Cooperative stage: 64 rows x 128 cols, f32 -> f16, coalesced float4.
    for (int i = t; i < 64 * 32; i += 256) {           // 8 iters/thread
        const int row = i >> 5;
        const int c4 = (i & 31) * 4;
        const int gr = n0 + row;
        const float4 xv = *(const float4*)&x[(size_t)(gr < N_NODES ? gr : N_NODES - 1) * 128 + c4];
        H4 tmp;
        tmp.h2[0] = __float22half2_rn(make_float2(xv.x, xv.y));
        tmp.h2[1] = __float22half2_rn(make_float2(xv.z, xv.w));
        *(uint2*)&sx[row][c4] = tmp.u;                 // 8B, 8B-aligned
    }
    __syncthreads();

    const int lane = t & 63;
    const int w = t >> 6;                    // wave id == head id
    const int q = lane >> 4;                 // quad
    const int n15 = lane & 15;
    const int j0 = (2 * w) * 16 + n15;       // col in tile 0 of this head
    const int j1 = (2 * w + 1) * 16 + n15;   // col in tile 1

    f32x4 acc[4][2] = {};                    // [m-group][n-tile]; static indices only
    f32x4 e0 = {0.f,0.f,0.f,0.f}, e1 = e0, e2 = e0, e3 = e0;   // wave-0 extra tile

    for (int kt = 0; kt < 4; ++kt) {
        const int k0 = kt * 32 + q * 8;
        H8 A0, A1, A2, A3, B0, B1;
        A0.v = *(const f16x8*)&sx[n15][k0];            // 16B ds_read_b128
        A1.v = *(const f16x8*)&sx[16 + n15][k0];
        A2.v = *(const f16x8*)&sx[32 + n15][k0];
        A3.v = *(const f16x8*)&sx[48 + n15][k0];
        {
            float w0[8], w1[8];
#pragma unroll
            for (int i = 0; i < 8; ++i) {
                w0[i] = W1[(size_t)(k0 + i) * 128 + j0];   // 64B runs, L2-hot
                w1[i] = W1[(size_t)(k0 + i) * 128 + j1];
            }
#pragma unroll
            for (int i = 0; i < 4; ++i) {
                B0.h2[i] = __float22half2_rn(make_float2(w0[2 * i], w0[2 * i + 1]));
                B1.h2[i] = __float22half2_rn(make_float2(w1[2 * i], w1[2 * i + 1]));
            }
        }
        acc[0][0] = __builtin_amdgcn_mfma_f32_16x16x32_f16(A0.v, B0.v, acc[0][0], 0, 0, 0);
        acc[0][1] = __builtin_amdgcn_mfma_f32_16x16x32_f16(A0.v, B1.v, acc[0][1], 0, 0, 0);
        acc[1][0] = __builtin_amdgcn_mfma_f32_16x16x32_f16(A1.v, B0.v, acc[1][0], 0, 0, 0);
        acc[1][1] = __builtin_amdgcn_mfma_f32_16x16x32_f16(A1.v, B1.v, acc[1][1], 0, 0, 0);
        acc[2][0] = __builtin_amdgcn_mfma_f32_16x16x32_f16(A2.v, B0.v, acc[2][0], 0, 0, 0);
        acc[2][1] = __builtin_amdgcn_mfma_f32_16x16x32_f16(A2.v, B1.v, acc[2][1], 0, 0, 0);
        acc[3][0] = __builtin_amdgcn_mfma_f32_16x16x32_f16(A3.v, B0.v, acc[3][0], 0, 0, 0);
        acc[3][1] = __builtin_amdgcn_mfma_f32_16x16x32_f16(A3.v, B1.v, acc[3][1], 0, 0, 0);
        if (w == 0) {                        // extra attention tile (cols: al h / ar h)
            H8 B2;
            B2.v = *(const f16x8*)&WaT1[n15 * 128 + k0];   // 16B, L1/L2-hot
            e0 = __builtin_amdgcn_mfma_f32_16x16x32_f16(A0.v, B2.v, e0, 0, 0, 0);
            e1 = __builtin_amdgcn_mfma_f32_16x16x32_f16(A1.v, B2.v, e1, 0, 0, 0);
            e2 = __builtin_amdgcn_mfma_f32_16x16x32_f16(A2.v, B2.v, e2, 0, 0, 0);
            e3 = __builtin_amdgcn_mfma_f32_16x16x32_f16(A3.v, B2.v, e3, 0, 0, 0);
        }
    }

    // Epilogue: D col = n15-based j, row = m*16 + q*4 + r. Stores only.
#pragma unroll
    for (int m = 0; m < 4; ++m) {
#pragma unroll
        for (int r = 0; r < 4; ++r) {
            const int node = n0 + m * 16 + q * 4 + r;
            if (node < N_NODES) {
                xw1h[(size_t)node * 128 + j0] = __float2half(acc[m][0][r]);   // 32B runs/quad
                xw1h[(size_t)node * 128 + j1] = __float2half(acc[m][1][r]);
            }
        }
    }
    if (w == 0) {
#pragma unroll
        for (int m = 0; m < 4; ++m) {
            const f32x4 em = (m == 0) ? e0 : (m == 1) ? e1 : (m == 2) ? e2 : e3;
#pragma unroll
            for (int r = 0; r < 4; ++r) {
                const int node = n0 + m * 16 + q * 4 + r;
                if (node < N_NODES) {
                    if (n15 < 4)      al1[(size_t)node * 4 + n15] = em[r];       // 16B run
                    else if (n15 < 8) ar1[(size_t)node * 4 + (n15 - 4)] = em[r]; // 16B run
                }
            }
        }
    }
}

// ---------------------------------------------------------------------------
// k_fill3: one 256-thread block per 256-node bucket (R5: 391 blocks vs 98 —
// >half the GPU was idle). LDS histogram + cursors counting sort; emits
// ioff/deg/ssrc. sbase summed from LDS-staged bcnt.
// ---------------------------------------------------------------------------
__global__ __launch_bounds__(256)
void k_fill3(const int* __restrict__ pairs, const int* __restrict__ bcnt,
             int* __restrict__ ioff, int* __restrict__ deg, int* __restrict__ ssrc) {
    const int bucket = blockIdx.x;
    const int t = threadIdx.x;
    const int cnt = bcnt[bucket];
    __shared__ int lhist[256];
    __shared__ int lcur[256];
    __shared__ int wsum[4];
    __shared__ int sbc[NBUCK + 1];
    __shared__ int sbase;
    lhist[t] = 0;
    for (int i = t; i < NBUCK; i += 256) sbc[i] = bcnt[i];   // coalesced
    __syncthreads();
    if (t == 0) {                            // sum lower buckets from LDS
        int b = 0;
        for (int k = 0; k < bucket; ++k) b += sbc[k];
        sbase = b;
    }
    for (int i = t; i < cnt; i += 256) {
        const int p = pairs[(size_t)bucket * PBSTRIDE + i];
        atomicAdd(&lhist[p & 255], 1);
    }
    __syncthreads();
    const int v = lhist[t];
    int inc = v;
    const int lane = t & 63, wid = t >> 6;
#pragma unroll
    for (int o = 1; o < 64; o <<= 1) {
        const int nv = __shfl_up(inc, o, 64);
        if (lane >= o) inc += nv;
    }
    if (lane == 63) wsum[wid] = inc;
    __syncthreads();
    if (t == 0) {
        int acc = 0;
#pragma unroll
        for (int k = 0; k < 4; ++k) { const int tv = wsum[k]; wsum[k] = acc; acc += tv; }
    }
    __syncthreads();
    const int gofs = sbase + (inc - v) + wsum[wid];   // global CSR offset of node d
    const int d = bucket * 256 + t;
    if (d < N_NODES) { ioff[d] = gofs; deg[d] = v; }
    lcur[t] = gofs;
    __syncthreads();
    for (int i = t; i < cnt; i += 256) {
        const int p = pairs[(size_t)bucket * PBSTRIDE + i];
        const int pos = atomicAdd(&lcur[p & 255], 1);      // LDS
        ssrc[pos] = p >> 8;
    }
}

// ---------------------------------------------------------------------------
// Layer 1 pull-aggregation — FROZEN (R10: VGPR 20, no epilogue preload;
// R1: no layer-2 fusion; R3: MLP-widening is a no-op -> per-CU miss-queue
// bound). One wave per dst node, zero barriers; uint4 gathers, 8 in flight.
// ---------------------------------------------------------------------------
__global__ __launch_bounds__(256)
void k_aggr1(const int* __restrict__ ssrc, const int* __restrict__ offs,
             const int* __restrict__ deg, const float* __restrict__ al1,
             const float* __restrict__ ar1, const __half* __restrict__ xw1h,
             const float* __restrict__ b1, __half* __restrict__ out1h) {
    const int lane = threadIdx.x & 63;
    const int d = blockIdx.x * 4 + (threadIdx.x >> 6);
    const int g = lane >> 4;                 // edge group 0..3
    const int c = lane & 15;                 // col group: features 8c..8c+7
    const int h = c >> 2;                    // head of this col group
    const int beg = offs[d];
    const int n = deg[d];
    const float arh = ar1[(size_t)d * 4 + h];
    float acc[8] = {0.f, 0.f, 0.f, 0.f, 0.f, 0.f, 0.f, 0.f};
    float dnm = 0.f;

    for (int base = 0; base < n; base += 8) {
#pragma unroll
        for (int u = 0; u < 2; ++u) {
            const int e = base + u * 4 + g;
            const bool p = e < n;
            const int s = ssrc[beg + (p ? e : 0)];         // L1-hot (sequential)
            float v = al1[(size_t)s * 4 + h] + arh;        // broadcast gather
            v = v > 0.f ? v : NEG_SLOPE * v;
            const float w = p ? __expf(v) : 0.f;
            const uint4 rv = *(const uint4*)&xw1h[(size_t)s * 128 + c * 8];
            const float2 f0 = __half22float2(*(const __half2*)&rv.x);
            const float2 f1 = __half22float2(*(const __half2*)&rv.y);
            const float2 f2 = __half22float2(*(const __half2*)&rv.z);
            const float2 f3 = __half22float2(*(const __half2*)&rv.w);
            acc[0] = fmaf(w, f0.x, acc[0]); acc[1] = fmaf(w, f0.y, acc[1]);
            acc[2] = fmaf(w, f1.x, acc[2]); acc[3] = fmaf(w, f1.y, acc[3]);
            acc[4] = fmaf(w, f2.x, acc[4]); acc[5] = fmaf(w, f2.y, acc[5]);
            acc[6] = fmaf(w, f3.x, acc[6]); acc[7] = fmaf(w, f3.y, acc[7]);
            dnm += w;
        }
    }
#pragma unroll
    for (int i = 0; i < 8; ++i) {
        acc[i] += __shfl_xor(acc[i], 16, 64);
        acc[i] += __shfl_xor(acc[i], 32, 64);
    }
    dnm += __shfl_xor(dnm, 16, 64);
    dnm += __shfl_xor(dnm, 32, 64);
    if (g == 0) {
        const float rc = 1.f / dnm;
        const float4 b01 = *(const float4*)&b1[c * 8];
        const float4 b23 = *(const float4*)&b1[c * 8 + 4];
        const float bb[8] = {b01.x, b01.y, b01.z, b01.w, b23.x, b23.y, b23.z, b23.w};
        __half ho[8];
#pragma unroll
        for (int i = 0; i < 8; ++i) {
            const float hv = acc[i] * rc + bb[i];
            ho[i] = __float2half(hv > 0.f ? hv : 0.f);     // bias + ReLU
        }
        *(uint4*)&out1h[(size_t)d * 128 + c * 8] = *(uint4*)ho;
    }
}

// ---------------------------------------------------------------------------
// Layer 2 GEMM via MFMA. 128 nodes/block, 4 waves, 2 M-tiles/wave.
// R5: al2/ar2 via extra MFMA with WaT2 (removes 64 shfl/wave epilogue).
// ---------------------------------------------------------------------------
__global__ __launch_bounds__(256)
void k_gemm2m(const __half* __restrict__ out1h, const float* __restrict__ W2,
              const _Float16* __restrict__ WaT2,
              __half* __restrict__ xw2h, float* __restrict__ al2, float* __restrict__ ar2) {
    const int t = threadIdx.x;
    const int lane = t & 63;
    const int w = t >> 6;
    const int q = lane >> 4;
    const int n15 = lane & 15;
    const int n0 = (int)blockIdx.x * 128 + w * 16;
    const int ra0 = n0 + n15;
    const int ra1 = n0 + 64 + n15;
    const size_t rowA0 = (ra0 < N_NODES) ? (size_t)ra0 : (size_t)(N_NODES - 1);
    const size_t rowA1 = (ra1 < N_NODES) ? (size_t)ra1 : (size_t)(N_NODES - 1);

    f32x4 acc0 = {0.f, 0.f, 0.f, 0.f}, acc1 = acc0;
    f32x4 e0 = acc0, e1 = acc0;
#pragma unroll
    for (int kt = 0; kt < 4; ++kt) {
        const int k0 = kt * 32 + q * 8;
        H8 A0, A1, B, B2;
        A0.v = *(const f16x8*)&out1h[rowA0 * 128 + k0];    // 16B, 32B runs/quad
        A1.v = *(const f16x8*)&out1h[rowA1 * 128 + k0];
        float wv[8];
#pragma unroll
        for (int i = 0; i < 8; ++i)
            wv[i] = W2[(size_t)(k0 + i) * 16 + n15];        // 64B runs, L1-hot
#pragma unroll
        for (int i = 0; i < 4; ++i)
            B.h2[i] = __float22half2_rn(make_float2(wv[2 * i], wv[2 * i + 1]));
        B2.v = *(const f16x8*)&WaT2[n15 * 128 + k0];        // 16B, hot
        acc0 = __builtin_amdgcn_mfma_f32_16x16x32_f16(A0.v, B.v, acc0, 0, 0, 0);
        acc1 = __builtin_amdgcn_mfma_f32_16x16x32_f16(A1.v, B.v, acc1, 0, 0, 0);
        e0   = __builtin_amdgcn_mfma_f32_16x16x32_f16(A0.v, B2.v, e0, 0, 0, 0);
        e1   = __builtin_amdgcn_mfma_f32_16x16x32_f16(A1.v, B2.v, e1, 0, 0, 0);
    }

    // C/D: col j = n15, row m = q*4 + r. Stores only.
#pragma unroll
    for (int m = 0; m < 2; ++m) {
        const f32x4 acc = m ? acc1 : acc0;
        const f32x4 em  = m ? e1 : e0;
#pragma unroll
        for (int r = 0; r < 4; ++r) {
            const int node = n0 + m * 64 + q * 4 + r;
            if (node < N_NODES) {
                xw2h[(size_t)node * 16 + n15] = __float2half(acc[r]);  // 32B runs/quad
                if (n15 == 0)      al2[node] = em[r];
                else if (n15 == 1) ar2[node] = em[r];
            }
        }
    }
}

// ---------------------------------------------------------------------------
// Layer 2 pull-aggregation: one wave per node; 32 edges in flight — mean
// degree 17 completes in ONE memory round (xw2h 3.2MB ~L2-resident).
// ---------------------------------------------------------------------------
__global__ __launch_bounds__(256)
void k_aggr2(const int* __restrict__ ssrc, const int* __restrict__ offs,
             const int* __restrict__ deg, const float* __restrict__ al2,
             const float* __restrict__ ar2, const __half* __restrict__ xw2h,
             const float* __restrict__ b2, float* __restrict__ out) {
    const int lane = threadIdx.x & 63;
    const int node = blockIdx.x * 4 + (threadIdx.x >> 6);
    const int j2 = lane & 7;                 // feature pair 2*j2, 2*j2+1
    const int eL = lane >> 3;                // 0..7
    const int beg = offs[node];
    const int n = deg[node];
    const float ard = ar2[node];
    float a0 = 0.f, a1 = 0.f, dnm = 0.f;
    for (int base = 0; base < n; base += 32) {
#pragma unroll
        for (int u = 0; u < 4; ++u) {
            const int e = base + u * 8 + eL;
            const bool p = e < n;
            const int s = ssrc[beg + (p ? e : 0)];
            float v = al2[s] + ard;
            v = v > 0.f ? v : NEG_SLOPE * v;
            const float w = p ? __expf(v) : 0.f;
            const float2 f = __half22float2(*(const __half2*)&xw2h[(size_t)s * 16 + j2 * 2]);
            a0 = fmaf(w, f.x, a0);
            a1 = fmaf(w, f.y, a1);
            dnm += w;
        }
    }
#pragma unroll
    for (int o = 8; o < 64; o <<= 1) {
        a0 += __shfl_xor(a0, o, 64);
        a1 += __shfl_xor(a1, o, 64);
        dnm += __shfl_xor(dnm, o, 64);
    }
    if (eL == 0) {
        out[(size_t)node * 16 + j2 * 2]     = a0 / dnm + b2[j2 * 2];
        out[(size_t)node * 16 + j2 * 2 + 1] = a1 / dnm + b2[j2 * 2 + 1];
    }
}

extern "C" void kernel_launch(void* const* d_in, const int* in_sizes, int n_in,
                              void* d_out, int out_size, void* d_ws, size_t ws_size,
                              hipStream_t stream) {
    const float* x      = (const float*)d_in[0];
    const int*   ei     = (const int*)d_in[1];
    const float* W1     = (const float*)d_in[2];
    const float* a_src1 = (const float*)d_in[3];
    const float* a_dst1 = (const float*)d_in[4];
    const float* b1     = (const float*)d_in[5];
    const float* W2     = (const float*)d_in[6];
    const float* a_src2 = (const float*)d_in[7];
    const float* a_dst2 = (const float*)d_in[8];
    const float* b2     = (const float*)d_in[9];
    float* out = (float*)d_out;

    // Workspace (byte-addressed). Aliases:
    //  - pairs (8.8MB packed) sits in out1h's region: consumed by k_fill3
    //    before k_aggr1 writes out1h.
    //  - xw2h/al2/ar2 sit in xw1h's region: written by k_gemm2m after k_aggr1
    //    is done with xw1h.
    //  - WaT1/WaT2 live past the end (written once by k_prep, read by
    //    gemm1_part / gemm2m; every large region gets fully overwritten so
    //    they cannot alias).
    char* wsb = (char*)d_ws;
    __half* xw1h = (__half*)wsb;                                  // N*128 half (25.6 MB)
    __half* xw2h = (__half*)wsb;                                  // N*16 half (alias)
    float*  al2  = (float*)(wsb + (size_t)N_NODES * 16 * 2);      // N fp32 (alias)
    float*  ar2  = al2 + N_NODES;                                 // N fp32 (alias)
    __half* out1h = (__half*)(wsb + (size_t)N_NODES * 128 * 2);   // N*128 half (25.6 MB)
    int*    pairs = (int*)out1h;                                  // NBUCK*PBSTRIDE int (8.8 MB)
    float*  al1  = (float*)(wsb + (size_t)N_NODES * 128 * 4);     // N*4 fp32
    float*  ar1  = al1 + (size_t)N_NODES * 4;                     // N*4
    int* ibcnt = (int*)(ar1 + (size_t)N_NODES * 4);               // NBUCK (512 reserved)
    int* ioff  = ibcnt + 512;                                     // N
    int* ideg  = ioff + N_NODES;                                  // N
    int* isrc  = ideg + N_NODES;                                  // E_TOT
    _Float16* WaT1 = (_Float16*)(isrc + E_TOT);                   // 16*128 f16 (4 KB)
    _Float16* WaT2 = WaT1 + 16 * 128;                             // 16*128 f16 (4 KB)

    // Prep: zero bcnt + fold attention vectors into W (replaces memset).
    k_prep<<<1, 128, 0, stream>>>(W1, a_src1, a_dst1, W2, a_src2, a_dst2,
                                  WaT1, WaT2, ibcnt);

    // Merged: MFMA layer-1 GEMM (staged-x, M=64, fused al/ar tile) + partition.
    k_gemm1_part<<<NGEMM + NPART, 256, 0, stream>>>(x, W1, WaT1, ei, ibcnt,
                                                    pairs, xw1h, al1, ar1);
    // Per-bucket counting sort -> CSR (ioff/ideg/isrc).
    k_fill3<<<NBUCK, 256, 0, stream>>>(pairs, ibcnt, ioff, ideg, isrc);

    // Layer 1 aggregation
    k_aggr1<<<N_NODES / 4, 256, 0, stream>>>(isrc, ioff, ideg, al1, ar1, xw1h, b1, out1h);

    // Layer 2 GEMM (MFMA, 2 M-tiles/wave, fused al2/ar2 tile)
    k_gemm2m<<<(N_NODES + 127) / 128, 256, 0, stream>>>(out1h, W2, WaT2, xw2h, al2, ar2);

    // Layer 2 aggregation
    k_aggr2<<<N_NODES / 4, 256, 0, stream>>>(isrc, ioff, ideg, al2, ar2, xw2h, b2, out);
}

// Round 6
// 312.592 us; speedup vs baseline: 1.1221x; 1.1221x over previous
//
#include <hip/hip_runtime.h>
#include <hip/hip_fp16.h>

#define N_NODES 100000
#define N_EDGES 1600000
#define E_TOT   (N_EDGES + N_NODES)   // 1,700,000 incl. self-loops
#define NEG_SLOPE 0.2f
#define PART_EPB 4096                 // edges per partition block
#define BSTRIDE 18432                 // slots per bucket region (mean 17408 + 7.8 sigma)
#define NGEMM ((N_NODES + 63) / 64)   // 1563 gemm blocks (64 rows each)
#define NPART ((E_TOT + PART_EPB - 1) / PART_EPB)   // 416 partition blocks
#define NFILL 128                     // fill blocks (buckets of 1024 nodes)

using f16x8 = __attribute__((ext_vector_type(8))) _Float16;
using f32x4 = __attribute__((ext_vector_type(4))) float;
union H8 { f16x8 v; _Float16 h[8]; __half2 h2[4]; };
union H4 { __half2 h2[2]; uint2 u; };

// R5 post-mortem (journal): WaT-fusion + serial k_prep + 391-bucket refactor
// regressed +52us (serial 1-block prep on critical path, wave-0 imbalance,
// unisolated bundle). All reverted; this round only re-pipelines fill3.

// ---------------------------------------------------------------------------
// k_part: edge bucket-partition (R4 code, now standalone so that k_fill can
// be merged with the layer-1 GEMM and hide under it).
// ---------------------------------------------------------------------------
__global__ __launch_bounds__(256)
void k_part(const int* __restrict__ ei, int* __restrict__ bcnt, int* __restrict__ pairs) {
    __shared__ int lcnt[128];
    __shared__ int lbase[128];
    const int t = threadIdx.x;
    const int base = (int)blockIdx.x * PART_EPB;
    if (t < 128) lcnt[t] = 0;
    __syncthreads();
    int sr[16], dr[16];
#pragma unroll
    for (int u = 0; u < 16; ++u) {
        const int e = base + u * 256 + t;    // coalesced
        if (e < E_TOT) {
            int s, d;
            if (e < N_EDGES) { s = ei[e]; d = ei[N_EDGES + e]; }
            else             { s = d = e - N_EDGES; }
            sr[u] = s; dr[u] = d;
            atomicAdd(&lcnt[d >> 10], 1);    // LDS
        } else dr[u] = -1;
    }
    __syncthreads();
    if (t < 128) {
        const int c = lcnt[t];
        lbase[t] = (c > 0) ? atomicAdd(&bcnt[t], c) : 0;   // global, 1/bucket
        lcnt[t] = 0;
    }
    __syncthreads();
#pragma unroll
    for (int u = 0; u < 16; ++u) {
        if (dr[u] >= 0) {
            const int bk = dr[u] >> 10;
            const int r = atomicAdd(&lcnt[bk], 1);         // LDS
            pairs[(size_t)bk * BSTRIDE + lbase[bk] + r] = (sr[u] << 10) | (dr[u] & 1023);
        }
    }
}

// ---------------------------------------------------------------------------
// Merged kernel (R6): blocks 0..NFILL-1 run the counting-sort fill (CSR
// build); blocks >= NFILL run the layer-1 MFMA GEMM (staged-x, M=64 — R4
// code unchanged). Fill depends only on k_part output; GEMM only on x/W1 —
// independent, so the fill's ~25-35us (98 blocks, >60% GPU idle standalone)
// hides under the 1563-block GEMM. Fill blocks come FIRST so they start
// immediately. LDS is a union: GEMM 17.4KB / fill 8.7KB -> occupancy as R4.
// ---------------------------------------------------------------------------
union SMem {
    _Float16 sx[64][136];                    // GEMM: 272B row stride (2-way = free, m136)
    struct { int lhist[1024]; int lcur[1024]; int sbc[128]; int wsum[4]; int sbase; } f;
};

__global__ __launch_bounds__(256)
void k_gemm1_fill(const float* __restrict__ x, const float* __restrict__ W1,
                  const float* __restrict__ a_src1, const float* __restrict__ a_dst1,
                  const int* __restrict__ bcnt, const int* __restrict__ pairs,
                  int* __restrict__ ioff, int* __restrict__ deg, int* __restrict__ ssrc,
                  __half* __restrict__ xw1h, float* __restrict__ al1, float* __restrict__ ar1) {
    __shared__ SMem sm;
    const int t = threadIdx.x;

    if (blockIdx.x < NFILL) {
        // ===== fill role: per-bucket counting sort -> CSR (256 threads,
        // 4 histogram slots/thread; bucketing identical to R4) =====
        const int bucket = blockIdx.x;
        const int cnt = bcnt[bucket];
        auto& F = sm.f;
        for (int i = t; i < 1024; i += 256) F.lhist[i] = 0;
        if (t < 128) F.sbc[t] = bcnt[t];     // coalesced stage
        __syncthreads();
        if (t == 0) {                        // edges in all lower buckets (LDS reads)
            int b = 0;
            for (int k = 0; k < bucket; ++k) b += F.sbc[k];
            F.sbase = b;
        }
        for (int i = t; i < cnt; i += 256) {
            const int p = pairs[(size_t)bucket * BSTRIDE + i];
            atomicAdd(&F.lhist[p & 1023], 1);
        }
        __syncthreads();
        // scan of 1024 hist slots by 256 threads: thread t owns slots 4t..4t+3
        const int h0 = F.lhist[4 * t], h1 = F.lhist[4 * t + 1];
        const int h2 = F.lhist[4 * t + 2], h3 = F.lhist[4 * t + 3];
        const int sum = h0 + h1 + h2 + h3;
        int inc = sum;
        const int lane = t & 63, wid = t >> 6;
#pragma unroll
        for (int o = 1; o < 64; o <<= 1) {
            const int nv = __shfl_up(inc, o, 64);
            if (lane >= o) inc += nv;
        }
        if (lane == 63) F.wsum[wid] = inc;
        __syncthreads();
        if (t == 0) {
            int acc = 0;
#pragma unroll
            for (int k = 0; k < 4; ++k) { const int tv = F.wsum[k]; F.wsum[k] = acc; acc += tv; }
        }
        __syncthreads();
        const int base = F.sbase + (inc - sum) + F.wsum[wid];  // CSR offset of slot 4t
        const int pp[4] = {base, base + h0, base + h0 + h1, base + h0 + h1 + h2};
        const int hh[4] = {h0, h1, h2, h3};
        const int d0 = (bucket << 10) + 4 * t;
#pragma unroll
        for (int i = 0; i < 4; ++i) {
            const int d = d0 + i;
            if (d < N_NODES) { ioff[d] = pp[i]; deg[d] = hh[i]; }
            F.lcur[4 * t + i] = pp[i];
        }
        __syncthreads();
        for (int i = t; i < cnt; i += 256) {
            const int p = pairs[(size_t)bucket * BSTRIDE + i];
            const int pos = atomicAdd(&F.lcur[p & 1023], 1);   // LDS
            ssrc[pos] = p >> 10;
        }
        return;
    }

    // ===== MFMA GEMM role (R4 code, blockIdx shifted by NFILL) =====
    const int n0 = ((int)blockIdx.x - NFILL) * 64;

    // Cooperative stage: 64 rows x 128 cols, f32 -> f16, coalesced float4.
    for (int i = t; i < 64 * 32; i += 256) {           // 8 iters/thread
        const int row = i >> 5;
        const int c4 = (i & 31) * 4;
        const int gr = n0 + row;
        const float4 xv = *(const float4*)&x[(size_t)(gr < N_NODES ? gr : N_NODES - 1) * 128 + c4];
        H4 tmp;
        tmp.h2[0] = __float22half2_rn(make_float2(xv.x, xv.y));
        tmp.h2[1] = __float22half2_rn(make_float2(xv.z, xv.w));
        *(uint2*)&sm.sx[row][c4] = tmp.u;              // 8B, 8B-aligned
    }
    __syncthreads();

    const int lane = t & 63;
    const int w = t >> 6;                    // wave id == head id
    const int q = lane >> 4;                 // quad
    const int n15 = lane & 15;
    const int j0 = (2 * w) * 16 + n15;       // col in tile 0 of this head
    const int j1 = (2 * w + 1) * 16 + n15;   // col in tile 1

    f32x4 acc[4][2] = {};                    // [m-group][n-tile]; static indices only

    for (int kt = 0; kt < 4; ++kt) {
        const int k0 = kt * 32 + q * 8;
        H8 A0, A1, A2, A3, B0, B1;
        A0.v = *(const f16x8*)&sm.sx[n15][k0];         // 16B ds_read_b128
        A1.v = *(const f16x8*)&sm.sx[16 + n15][k0];
        A2.v = *(const f16x8*)&sm.sx[32 + n15][k0];
        A3.v = *(const f16x8*)&sm.sx[48 + n15][k0];
        {
            float w0[8], w1[8];
#pragma unroll
            for (int i = 0; i < 8; ++i) {
                w0[i] = W1[(size_t)(k0 + i) * 128 + j0];   // 64B runs, L2-hot
                w1[i] = W1[(size_t)(k0 + i) * 128 + j1];
            }
#pragma unroll
            for (int i = 0; i < 4; ++i) {
                B0.h2[i] = __float22half2_rn(make_float2(w0[2 * i], w0[2 * i + 1]));
                B1.h2[i] = __float22half2_rn(make_float2(w1[2 * i], w1[2 * i + 1]));
            }
        }
        acc[0][0] = __builtin_amdgcn_mfma_f32_16x16x32_f16(A0.v, B0.v, acc[0][0], 0, 0, 0);
        acc[0][1] = __builtin_amdgcn_mfma_f32_16x16x32_f16(A0.v, B1.v, acc[0][1], 0, 0, 0);
        acc[1][0] = __builtin_amdgcn_mfma_f32_16x16x32_f16(A1.v, B0.v, acc[1][0], 0, 0, 0);
        acc[1][1] = __builtin_amdgcn_mfma_f32_16x16x32_f16(A1.v, B1.v, acc[1][1], 0, 0, 0);
        acc[2][0] = __builtin_amdgcn_mfma_f32_16x16x32_f16(A2.v, B0.v, acc[2][0], 0, 0, 0);
        acc[2][1] = __builtin_amdgcn_mfma_f32_16x16x32_f16(A2.v, B1.v, acc[2][1], 0, 0, 0);
        acc[3][0] = __builtin_amdgcn_mfma_f32_16x16x32_f16(A3.v, B0.v, acc[3][0], 0, 0, 0);
        acc[3][1] = __builtin_amdgcn_mfma_f32_16x16x32_f16(A3.v, B1.v, acc[3][1], 0, 0, 0);
    }

    // Epilogue: D col = n15-based j, row m*16 + q*4 + r. Fused attn dots.
    const float as0 = a_src1[j0], as1 = a_src1[j1];
    const float ad0 = a_dst1[j0], ad1 = a_dst1[j1];
#pragma unroll
    for (int m = 0; m < 4; ++m) {
#pragma unroll
        for (int r = 0; r < 4; ++r) {
            const int node = n0 + m * 16 + q * 4 + r;
            const float vA = acc[m][0][r], vB = acc[m][1][r];
            const bool ok = node < N_NODES;
            if (ok) {
                xw1h[(size_t)node * 128 + j0] = __float2half(vA);   // 32B runs/quad
                xw1h[(size_t)node * 128 + j1] = __float2half(vB);
            }
            float ps = vA * as0 + vB * as1;
            float pd = vA * ad0 + vB * ad1;
#pragma unroll
            for (int o = 1; o < 16; o <<= 1) {   // reduce over the 16 j-lanes (quad preserved)
                ps += __shfl_xor(ps, o, 64);
                pd += __shfl_xor(pd, o, 64);
            }
            if (n15 == 0 && ok) {
                al1[(size_t)node * 4 + w] = ps;
                ar1[(size_t)node * 4 + w] = pd;
            }
        }
    }
}

// ---------------------------------------------------------------------------
// Layer 1 pull-aggregation — FROZEN (R10: VGPR 20, no epilogue preload;
// R1: no layer-2 fusion; R3: MLP-widening is a no-op -> per-CU miss-queue
// bound). One wave per dst node, zero barriers; uint4 gathers, 8 in flight.
// ---------------------------------------------------------------------------
__global__ __launch_bounds__(256)
void k_aggr1(const int* __restrict__ ssrc, const int* __restrict__ offs,
             const int* __restrict__ deg, const float* __restrict__ al1,
             const float* __restrict__ ar1, const __half* __restrict__ xw1h,
             const float* __restrict__ b1, __half* __restrict__ out1h) {
    const int lane = threadIdx.x & 63;
    const int d = blockIdx.x * 4 + (threadIdx.x >> 6);
    const int g = lane >> 4;                 // edge group 0..3
    const int c = lane & 15;                 // col group: features 8c..8c+7
    const int h = c >> 2;                    // head of this col group
    const int beg = offs[d];
    const int n = deg[d];
    const float arh = ar1[(size_t)d * 4 + h];
    float acc[8] = {0.f, 0.f, 0.f, 0.f, 0.f, 0.f, 0.f, 0.f};
    float dnm = 0.f;

    for (int base = 0; base < n; base += 8) {
#pragma unroll
        for (int u = 0; u < 2; ++u) {
            const int e = base + u * 4 + g;
            const bool p = e < n;
            const int s = ssrc[beg + (p ? e : 0)];         // L1-hot (sequential)
            float v = al1[(size_t)s * 4 + h] + arh;        // broadcast gather
            v = v > 0.f ? v : NEG_SLOPE * v;
            const float w = p ? __expf(v) : 0.f;
            const uint4 rv = *(const uint4*)&xw1h[(size_t)s * 128 + c * 8];
            const float2 f0 = __half22float2(*(const __half2*)&rv.x);
            const float2 f1 = __half22float2(*(const __half2*)&rv.y);
            const float2 f2 = __half22float2(*(const __half2*)&rv.z);
            const float2 f3 = __half22float2(*(const __half2*)&rv.w);
            acc[0] = fmaf(w, f0.x, acc[0]); acc[1] = fmaf(w, f0.y, acc[1]);
            acc[2] = fmaf(w, f1.x, acc[2]); acc[3] = fmaf(w, f1.y, acc[3]);
            acc[4] = fmaf(w, f2.x, acc[4]); acc[5] = fmaf(w, f2.y, acc[5]);
            acc[6] = fmaf(w, f3.x, acc[6]); acc[7] = fmaf(w, f3.y, acc[7]);
            dnm += w;
        }
    }
#pragma unroll
    for (int i = 0; i < 8; ++i) {
        acc[i] += __shfl_xor(acc[i], 16, 64);
        acc[i] += __shfl_xor(acc[i], 32, 64);
    }
    dnm += __shfl_xor(dnm, 16, 64);
    dnm += __shfl_xor(dnm, 32, 64);
    if (g == 0) {
        const float rc = 1.f / dnm;
        const float4 b01 = *(const float4*)&b1[c * 8];
        const float4 b23 = *(const float4*)&b1[c * 8 + 4];
        const float bb[8] = {b01.x, b01.y, b01.z, b01.w, b23.x, b23.y, b23.z, b23.w};
        __half ho[8];
#pragma unroll
        for (int i = 0; i < 8; ++i) {
            const float hv = acc[i] * rc + bb[i];
            ho[i] = __float2half(hv > 0.f ? hv : 0.f);     // bias + ReLU
        }
        *(uint4*)&out1h[(size_t)d * 128 + c * 8] = *(uint4*)ho;
    }
}

// ---------------------------------------------------------------------------
// Layer 2 GEMM via MFMA. 128 nodes/block, 4 waves, 2 M-tiles/wave (R4).
// A-frags direct 16B loads of out1h; W2 scalar-loads L1-hot; fused a2 dots.
// ---------------------------------------------------------------------------
__global__ __launch_bounds__(256)
void k_gemm2m(const __half* __restrict__ out1h, const float* __restrict__ W2,
              const float* __restrict__ a_src2, const float* __restrict__ a_dst2,
              __half* __restrict__ xw2h, float* __restrict__ al2, float* __restrict__ ar2) {
    const int t = threadIdx.x;
    const int lane = t & 63;
    const int w = t >> 6;
    const int q = lane >> 4;
    const int n15 = lane & 15;
    const int n0 = (int)blockIdx.x * 128 + w * 16;
    const int ra0 = n0 + n15;
    const int ra1 = n0 + 64 + n15;
    const size_t rowA0 = (ra0 < N_NODES) ? (size_t)ra0 : (size_t)(N_NODES - 1);
    const size_t rowA1 = (ra1 < N_NODES) ? (size_t)ra1 : (size_t)(N_NODES - 1);

    f32x4 acc0 = {0.f, 0.f, 0.f, 0.f}, acc1 = acc0;
#pragma unroll
    for (int kt = 0; kt < 4; ++kt) {
        const int k0 = kt * 32 + q * 8;
        H8 A0, A1, B;
        A0.v = *(const f16x8*)&out1h[rowA0 * 128 + k0];    // 16B, 32B runs/quad
        A1.v = *(const f16x8*)&out1h[rowA1 * 128 + k0];
        float wv[8];
#pragma unroll
        for (int i = 0; i < 8; ++i)
            wv[i] = W2[(size_t)(k0 + i) * 16 + n15];        // 64B runs, L1-hot
#pragma unroll
        for (int i = 0; i < 4; ++i)
            B.h2[i] = __float22half2_rn(make_float2(wv[2 * i], wv[2 * i + 1]));
        acc0 = __builtin_amdgcn_mfma_f32_16x16x32_f16(A0.v, B.v, acc0, 0, 0, 0);
        acc1 = __builtin_amdgcn_mfma_f32_16x16x32_f16(A1.v, B.v, acc1, 0, 0, 0);
    }

    // C/D: col j = n15, row m = q*4 + r. Fused attention dots (reduce over j).
    const float as = a_src2[n15], ad = a_dst2[n15];
#pragma unroll
    for (int m = 0; m < 2; ++m) {
        const f32x4 acc = m ? acc1 : acc0;
#pragma unroll
        for (int r = 0; r < 4; ++r) {
            const int node = n0 + m * 64 + q * 4 + r;
            float ps = acc[r] * as;
            float pd = acc[r] * ad;
#pragma unroll
            for (int o = 1; o < 16; o <<= 1) {
                ps += __shfl_xor(ps, o, 64);
                pd += __shfl_xor(pd, o, 64);
            }
            if (node < N_NODES) {
                xw2h[(size_t)node * 16 + n15] = __float2half(acc[r]);  // 32B runs/quad
                if (n15 == 0) { al2[node] = ps; ar2[node] = pd; }
            }
        }
    }
}

// ---------------------------------------------------------------------------
// Layer 2 pull-aggregation: one wave per node; 32 edges in flight — mean
// degree 17 completes in ONE memory round (xw2h 3.2MB ~L2-resident).
// ---------------------------------------------------------------------------
__global__ __launch_bounds__(256)
void k_aggr2(const int* __restrict__ ssrc, const int* __restrict__ offs,
             const int* __restrict__ deg, const float* __restrict__ al2,
             const float* __restrict__ ar2, const __half* __restrict__ xw2h,
             const float* __restrict__ b2, float* __restrict__ out) {
    const int lane = threadIdx.x & 63;
    const int node = blockIdx.x * 4 + (threadIdx.x >> 6);
    const int j2 = lane & 7;                 // feature pair 2*j2, 2*j2+1
    const int eL = lane >> 3;                // 0..7
    const int beg = offs[node];
    const int n = deg[node];
    const float ard = ar2[node];
    float a0 = 0.f, a1 = 0.f, dnm = 0.f;
    for (int base = 0; base < n; base += 32) {
#pragma unroll
        for (int u = 0; u < 4; ++u) {
            const int e = base + u * 8 + eL;
            const bool p = e < n;
            const int s = ssrc[beg + (p ? e : 0)];
            float v = al2[s] + ard;
            v = v > 0.f ? v : NEG_SLOPE * v;
            const float w = p ? __expf(v) : 0.f;
            const float2 f = __half22float2(*(const __half2*)&xw2h[(size_t)s * 16 + j2 * 2]);
            a0 = fmaf(w, f.x, a0);
            a1 = fmaf(w, f.y, a1);
            dnm += w;
        }
    }
#pragma unroll
    for (int o = 8; o < 64; o <<= 1) {
        a0 += __shfl_xor(a0, o, 64);
        a1 += __shfl_xor(a1, o, 64);
        dnm += __shfl_xor(dnm, o, 64);
    }
    if (eL == 0) {
        out[(size_t)node * 16 + j2 * 2]     = a0 / dnm + b2[j2 * 2];
        out[(size_t)node * 16 + j2 * 2 + 1] = a1 / dnm + b2[j2 * 2 + 1];
    }
}

extern "C" void kernel_launch(void* const* d_in, const int* in_sizes, int n_in,
                              void* d_out, int out_size, void* d_ws, size_t ws_size,
                              hipStream_t stream) {
    const float* x      = (const float*)d_in[0];
    const int*   ei     = (const int*)d_in[1];
    const float* W1     = (const float*)d_in[2];
    const float* a_src1 = (const float*)d_in[3];
    const float* a_dst1 = (const float*)d_in[4];
    const float* b1     = (const float*)d_in[5];
    const float* W2     = (const float*)d_in[6];
    const float* a_src2 = (const float*)d_in[7];
    const float* a_dst2 = (const float*)d_in[8];
    const float* b2     = (const float*)d_in[9];
    float* out = (float*)d_out;

    // Workspace (byte-addressed). Aliases:
    //  - pairs (9.4MB packed) sits in out1h's region: consumed by the fill
    //    role of k_gemm1_fill before k_aggr1 writes out1h.
    //  - xw2h/al2/ar2 sit in xw1h's region: written by k_gemm2m after k_aggr1
    //    is done with xw1h.
    char* wsb = (char*)d_ws;
    __half* xw1h = (__half*)wsb;                                  // N*128 half (25.6 MB)
    __half* xw2h = (__half*)wsb;                                  // N*16 half (alias)
    float*  al2  = (float*)(wsb + (size_t)N_NODES * 16 * 2);      // N fp32 (alias)
    float*  ar2  = al2 + N_NODES;                                 // N fp32 (alias)
    __half* out1h = (__half*)(wsb + (size_t)N_NODES * 128 * 2);   // N*128 half (25.6 MB)
    int*    pairs = (int*)out1h;                                  // 128*BSTRIDE int (alias, 9.4 MB)
    float*  al1  = (float*)(wsb + (size_t)N_NODES * 128 * 4);     // N*4 fp32
    float*  ar1  = al1 + (size_t)N_NODES * 4;                     // N*4
    int* ibcnt = (int*)(ar1 + (size_t)N_NODES * 4);               // 128 (zeroed)
    int* ioff  = ibcnt + 128;                                     // N
    int* ideg  = ioff + N_NODES;                                  // N
    int* isrc  = ideg + N_NODES;                                  // E_TOT

    hipMemsetAsync(ibcnt, 0, 128 * sizeof(int), stream);

    // Edge bucket-partition (standalone; ~BW-bound on 21MB).
    k_part<<<NPART, 256, 0, stream>>>(ei, ibcnt, pairs);

    // Merged: CSR fill (blocks 0..127, hidden) + MFMA layer-1 GEMM.
    k_gemm1_fill<<<NFILL + NGEMM, 256, 0, stream>>>(x, W1, a_src1, a_dst1,
                                                    ibcnt, pairs, ioff, ideg, isrc,
                                                    xw1h, al1, ar1);

    // Layer 1 aggregation
    k_aggr1<<<N_NODES / 4, 256, 0, stream>>>(isrc, ioff, ideg, al1, ar1, xw1h, b1, out1h);

    // Layer 2 GEMM (MFMA, 2 M-tiles/wave) + fused attention dots
    k_gemm2m<<<(N_NODES + 127) / 128, 256, 0, stream>>>(out1h, W2, a_src2, a_dst2, xw2h, al2, ar2);

    // Layer 2 aggregation
    k_aggr2<<<N_NODES / 4, 256, 0, stream>>>(isrc, ioff, ideg, al2, ar2, xw2h, b2, out);
}

// Round 7
// 296.881 us; speedup vs baseline: 1.1815x; 1.0529x over previous
//
#include <hip/hip_runtime.h>
#include <hip/hip_fp16.h>

#define N_NODES 100000
#define N_EDGES 1600000
#define E_TOT   (N_EDGES + N_NODES)   // 1,700,000 incl. self-loops
#define NEG_SLOPE 0.2f
#define PART_EPB 4096                 // edges per partition block
#define NBUCK 391                     // 256-node buckets (R7: was 128x1024 -> 98 active blocks)
#define PBSTRIDE 5376                 // slots/bucket: mean 4352 + ~15 sigma
#define NGEMM ((N_NODES + 63) / 64)   // 1563 gemm blocks (64 rows each)
#define NPART ((E_TOT + PART_EPB - 1) / PART_EPB)   // 416 partition blocks

using f16x8 = __attribute__((ext_vector_type(8))) _Float16;
using f32x4 = __attribute__((ext_vector_type(4))) float;
union H8 { f16x8 v; _Float16 h[8]; __half2 h2[4]; };
union H4 { __half2 h2[2]; uint2 u; };

// Journal: R5 (WaT-fusion + serial prep + bucket refactor, bundled) = +52us;
// R6 (fill merged at 256thr/bucket + standalone k_part) = +14us. Both reverted.
// R7 = R4 + ONE change: 256-node buckets -> 391 fill blocks (CU coverage
// 98 -> 391; per-thread iterations invariant). Everything else is R4 code.

// ---------------------------------------------------------------------------
// Merged kernel: blocks < NGEMM do the layer-1 GEMM via MFMA (staged-x LDS
// tile, M=64). Blocks >= NGEMM do the edge bucket-partition (independent
// roles -> one dispatch, partition hides under the GEMM).
// ---------------------------------------------------------------------------
__global__ __launch_bounds__(256)
void k_gemm1_part(const float* __restrict__ x, const float* __restrict__ W1,
                  const float* __restrict__ a_src1, const float* __restrict__ a_dst1,
                  const int* __restrict__ ei, int* __restrict__ bcnt, int* __restrict__ pairs,
                  __half* __restrict__ xw1h, float* __restrict__ al1, float* __restrict__ ar1) {
    __shared__ int lcnt[NBUCK + 1];
    __shared__ int lbase[NBUCK + 1];
    __shared__ _Float16 sx[64][136];         // 17.4 KB; 272B row stride (2-way = free, m136)
    const int t = threadIdx.x;

    if (blockIdx.x >= NGEMM) {
        // ===== edge-partition role (R4 structure; 391 buckets of 256 nodes) =====
        const int base = ((int)blockIdx.x - NGEMM) * PART_EPB;
        for (int i = t; i < NBUCK; i += 256) lcnt[i] = 0;
        __syncthreads();
        int sr[16], dr[16];
#pragma unroll
        for (int u = 0; u < 16; ++u) {
            const int e = base + u * 256 + t;    // coalesced
            if (e < E_TOT) {
                int s, d;
                if (e < N_EDGES) { s = ei[e]; d = ei[N_EDGES + e]; }
                else             { s = d = e - N_EDGES; }
                sr[u] = s; dr[u] = d;
                atomicAdd(&lcnt[d >> 8], 1);     // LDS
            } else dr[u] = -1;
        }
        __syncthreads();
        for (int i = t; i < NBUCK; i += 256) {
            const int c = lcnt[i];
            lbase[i] = (c > 0) ? atomicAdd(&bcnt[i], c) : 0;   // global, 1/bucket
            lcnt[i] = 0;
        }
        __syncthreads();
#pragma unroll
        for (int u = 0; u < 16; ++u) {
            if (dr[u] >= 0) {
                const int bk = dr[u] >> 8;
                const int r = atomicAdd(&lcnt[bk], 1);         // LDS
                pairs[(size_t)bk * PBSTRIDE + lbase[bk] + r] = (sr[u] << 8) | (dr[u] & 255);
            }
        }
        return;
    }

    // ===== MFMA GEMM role (R4 code, unchanged) =====
    const int n0 = (int)blockIdx.x * 64;

    // Cooperative stage: 64 rows x 128 cols, f32 -> f16, coalesced float4.
    for (int i = t; i < 64 * 32; i += 256) {           // 8 iters/thread
        const int row = i >> 5;
        const int c4 = (i & 31) * 4;
        const int gr = n0 + row;
        const float4 xv = *(const float4*)&x[(size_t)(gr < N_NODES ? gr : N_NODES - 1) * 128 + c4];
        H4 tmp;
        tmp.h2[0] = __float22half2_rn(make_float2(xv.x, xv.y));
        tmp.h2[1] = __float22half2_rn(make_float2(xv.z, xv.w));
        *(uint2*)&sx[row][c4] = tmp.u;                 // 8B, 8B-aligned
    }
    __syncthreads();

    const int lane = t & 63;
    const int w = t >> 6;                    // wave id == head id
    const int q = lane >> 4;                 // quad
    const int n15 = lane & 15;
    const int j0 = (2 * w) * 16 + n15;       // col in tile 0 of this head
    const int j1 = (2 * w + 1) * 16 + n15;   // col in tile 1

    f32x4 acc[4][2] = {};                    // [m-group][n-tile]; static indices only

    for (int kt = 0; kt < 4; ++kt) {
        const int k0 = kt * 32 + q * 8;
        H8 A0, A1, A2, A3, B0, B1;
        A0.v = *(const f16x8*)&sx[n15][k0];            // 16B ds_read_b128
        A1.v = *(const f16x8*)&sx[16 + n15][k0];
        A2.v = *(const f16x8*)&sx[32 + n15][k0];
        A3.v = *(const f16x8*)&sx[48 + n15][k0];
        {
            float w0[8], w1[8];
#pragma unroll
            for (int i = 0; i < 8; ++i) {
                w0[i] = W1[(size_t)(k0 + i) * 128 + j0];   // 64B runs, L2-hot
                w1[i] = W1[(size_t)(k0 + i) * 128 + j1];
            }
#pragma unroll
            for (int i = 0; i < 4; ++i) {
                B0.h2[i] = __float22half2_rn(make_float2(w0[2 * i], w0[2 * i + 1]));
                B1.h2[i] = __float22half2_rn(make_float2(w1[2 * i], w1[2 * i + 1]));
            }
        }
        acc[0][0] = __builtin_amdgcn_mfma_f32_16x16x32_f16(A0.v, B0.v, acc[0][0], 0, 0, 0);
        acc[0][1] = __builtin_amdgcn_mfma_f32_16x16x32_f16(A0.v, B1.v, acc[0][1], 0, 0, 0);
        acc[1][0] = __builtin_amdgcn_mfma_f32_16x16x32_f16(A1.v, B0.v, acc[1][0], 0, 0, 0);
        acc[1][1] = __builtin_amdgcn_mfma_f32_16x16x32_f16(A1.v, B1.v, acc[1][1], 0, 0, 0);
        acc[2][0] = __builtin_amdgcn_mfma_f32_16x16x32_f16(A2.v, B0.v, acc[2][0], 0, 0, 0);
        acc[2][1] = __builtin_amdgcn_mfma_f32_16x16x32_f16(A2.v, B1.v, acc[2][1], 0, 0, 0);
        acc[3][0] = __builtin_amdgcn_mfma_f32_16x16x32_f16(A3.v, B0.v, acc[3][0], 0, 0, 0);
        acc[3][1] = __builtin_amdgcn_mfma_f32_16x16x32_f16(A3.v, B1.v, acc[3][1], 0, 0, 0);
    }

    // Epilogue: D col = n15-based j, row m*16 + q*4 + r. Fused attn dots.
    const float as0 = a_src1[j0], as1 = a_src1[j1];
    const float ad0 = a_dst1[j0], ad1 = a_dst1[j1];
#pragma unroll
    for (int m = 0; m < 4; ++m) {
#pragma unroll
        for (int r = 0; r < 4; ++r) {
            const int node = n0 + m * 16 + q * 4 + r;
            const float vA = acc[m][0][r], vB = acc[m][1][r];
            const bool ok = node < N_NODES;
            if (ok) {
                xw1h[(size_t)node * 128 + j0] = __float2half(vA);   // 32B runs/quad
                xw1h[(size_t)node * 128 + j1] = __float2half(vB);
            }
            float ps = vA * as0 + vB * as1;
            float pd = vA * ad0 + vB * ad1;
#pragma unroll
            for (int o = 1; o < 16; o <<= 1) {   // reduce over the 16 j-lanes (quad preserved)
                ps += __shfl_xor(ps, o, 64);
                pd += __shfl_xor(pd, o, 64);
            }
            if (n15 == 0 && ok) {
                al1[(size_t)node * 4 + w] = ps;
                ar1[(size_t)node * 4 + w] = pd;
            }
        }
    }
}

// ---------------------------------------------------------------------------
// k_fill3 (R7): one 256-thread block per 256-node bucket -> 391 blocks
// (was 98 active at 1024-node buckets: <40% CU coverage, the fill's only
// lever since per-thread iteration count is bucket-size invariant).
// LDS histogram + cursors counting sort; emits ioff/deg/ssrc.
// ---------------------------------------------------------------------------
__global__ __launch_bounds__(256)
void k_fill3(const int* __restrict__ pairs, const int* __restrict__ bcnt,
             int* __restrict__ ioff, int* __restrict__ deg, int* __restrict__ ssrc) {
    const int bucket = blockIdx.x;
    const int t = threadIdx.x;
    const int cnt = bcnt[bucket];
    __shared__ int lhist[256];
    __shared__ int lcur[256];
    __shared__ int wsum[4];
    __shared__ int sbc[NBUCK + 1];
    __shared__ int sbase;
    lhist[t] = 0;
    for (int i = t; i < NBUCK; i += 256) sbc[i] = bcnt[i];   // coalesced stage
    __syncthreads();
    if (t == 0) {                            // edges in all lower buckets (LDS, pipelined)
        int b = 0;
        for (int k = 0; k < bucket; ++k) b += sbc[k];
        sbase = b;
    }
    for (int i = t; i < cnt; i += 256) {
        const int p = pairs[(size_t)bucket * PBSTRIDE + i];
        atomicAdd(&lhist[p & 255], 1);
    }
    __syncthreads();
    const int v = lhist[t];
    int inc = v;
    const int lane = t & 63, wid = t >> 6;
#pragma unroll
    for (int o = 1; o < 64; o <<= 1) {
        const int nv = __shfl_up(inc, o, 64);
        if (lane >= o) inc += nv;
    }
    if (lane == 63) wsum[wid] = inc;
    __syncthreads();
    if (t == 0) {
        int acc = 0;
#pragma unroll
        for (int k = 0; k < 4; ++k) { const int tv = wsum[k]; wsum[k] = acc; acc += tv; }
    }
    __syncthreads();
    const int gofs = sbase + (inc - v) + wsum[wid];   // global CSR offset of node d
    const int d = bucket * 256 + t;
    if (d < N_NODES) { ioff[d] = gofs; deg[d] = v; }
    lcur[t] = gofs;
    __syncthreads();
    for (int i = t; i < cnt; i += 256) {
        const int p = pairs[(size_t)bucket * PBSTRIDE + i];
        const int pos = atomicAdd(&lcur[p & 255], 1);      // LDS
        ssrc[pos] = p >> 8;
    }
}

// ---------------------------------------------------------------------------
// Layer 1 pull-aggregation — FROZEN (R10: VGPR 20, no epilogue preload;
// R1: no layer-2 fusion; R3: MLP-widening is a no-op -> per-CU miss-queue
// bound). One wave per dst node, zero barriers; uint4 gathers, 8 in flight.
// ---------------------------------------------------------------------------
__global__ __launch_bounds__(256)
void k_aggr1(const int* __restrict__ ssrc, const int* __restrict__ offs,
             const int* __restrict__ deg, const float* __restrict__ al1,
             const float* __restrict__ ar1, const __half* __restrict__ xw1h,
             const float* __restrict__ b1, __half* __restrict__ out1h) {
    const int lane = threadIdx.x & 63;
    const int d = blockIdx.x * 4 + (threadIdx.x >> 6);
    const int g = lane >> 4;                 // edge group 0..3
    const int c = lane & 15;                 // col group: features 8c..8c+7
    const int h = c >> 2;                    // head of this col group
    const int beg = offs[d];
    const int n = deg[d];
    const float arh = ar1[(size_t)d * 4 + h];
    float acc[8] = {0.f, 0.f, 0.f, 0.f, 0.f, 0.f, 0.f, 0.f};
    float dnm = 0.f;

    for (int base = 0; base < n; base += 8) {
#pragma unroll
        for (int u = 0; u < 2; ++u) {
            const int e = base + u * 4 + g;
            const bool p = e < n;
            const int s = ssrc[beg + (p ? e : 0)];         // L1-hot (sequential)
            float v = al1[(size_t)s * 4 + h] + arh;        // broadcast gather
            v = v > 0.f ? v : NEG_SLOPE * v;
            const float w = p ? __expf(v) : 0.f;
            const uint4 rv = *(const uint4*)&xw1h[(size_t)s * 128 + c * 8];
            const float2 f0 = __half22float2(*(const __half2*)&rv.x);
            const float2 f1 = __half22float2(*(const __half2*)&rv.y);
            const float2 f2 = __half22float2(*(const __half2*)&rv.z);
            const float2 f3 = __half22float2(*(const __half2*)&rv.w);
            acc[0] = fmaf(w, f0.x, acc[0]); acc[1] = fmaf(w, f0.y, acc[1]);
            acc[2] = fmaf(w, f1.x, acc[2]); acc[3] = fmaf(w, f1.y, acc[3]);
            acc[4] = fmaf(w, f2.x, acc[4]); acc[5] = fmaf(w, f2.y, acc[5]);
            acc[6] = fmaf(w, f3.x, acc[6]); acc[7] = fmaf(w, f3.y, acc[7]);
            dnm += w;
        }
    }
#pragma unroll
    for (int i = 0; i < 8; ++i) {
        acc[i] += __shfl_xor(acc[i], 16, 64);
        acc[i] += __shfl_xor(acc[i], 32, 64);
    }
    dnm += __shfl_xor(dnm, 16, 64);
    dnm += __shfl_xor(dnm, 32, 64);
    if (g == 0) {
        const float rc = 1.f / dnm;
        const float4 b01 = *(const float4*)&b1[c * 8];
        const float4 b23 = *(const float4*)&b1[c * 8 + 4];
        const float bb[8] = {b01.x, b01.y, b01.z, b01.w, b23.x, b23.y, b23.z, b23.w};
        __half ho[8];
#pragma unroll
        for (int i = 0; i < 8; ++i) {
            const float hv = acc[i] * rc + bb[i];
            ho[i] = __float2half(hv > 0.f ? hv : 0.f);     // bias + ReLU
        }
        *(uint4*)&out1h[(size_t)d * 128 + c * 8] = *(uint4*)ho;
    }
}

// ---------------------------------------------------------------------------
// Layer 2 GEMM via MFMA. 128 nodes/block, 4 waves, 2 M-tiles/wave (R4).
// A-frags direct 16B loads of out1h; W2 scalar-loads L1-hot; fused a2 dots.
// ---------------------------------------------------------------------------
__global__ __launch_bounds__(256)
void k_gemm2m(const __half* __restrict__ out1h, const float* __restrict__ W2,
              const float* __restrict__ a_src2, const float* __restrict__ a_dst2,
              __half* __restrict__ xw2h, float* __restrict__ al2, float* __restrict__ ar2) {
    const int t = threadIdx.x;
    const int lane = t & 63;
    const int w = t >> 6;
    const int q = lane >> 4;
    const int n15 = lane & 15;
    const int n0 = (int)blockIdx.x * 128 + w * 16;
    const int ra0 = n0 + n15;
    const int ra1 = n0 + 64 + n15;
    const size_t rowA0 = (ra0 < N_NODES) ? (size_t)ra0 : (size_t)(N_NODES - 1);
    const size_t rowA1 = (ra1 < N_NODES) ? (size_t)ra1 : (size_t)(N_NODES - 1);

    f32x4 acc0 = {0.f, 0.f, 0.f, 0.f}, acc1 = acc0;
#pragma unroll
    for (int kt = 0; kt < 4; ++kt) {
        const int k0 = kt * 32 + q * 8;
        H8 A0, A1, B;
        A0.v = *(const f16x8*)&out1h[rowA0 * 128 + k0];    // 16B, 32B runs/quad
        A1.v = *(const f16x8*)&out1h[rowA1 * 128 + k0];
        float wv[8];
#pragma unroll
        for (int i = 0; i < 8; ++i)
            wv[i] = W2[(size_t)(k0 + i) * 16 + n15];        // 64B runs, L1-hot
#pragma unroll
        for (int i = 0; i < 4; ++i)
            B.h2[i] = __float22half2_rn(make_float2(wv[2 * i], wv[2 * i + 1]));
        acc0 = __builtin_amdgcn_mfma_f32_16x16x32_f16(A0.v, B.v, acc0, 0, 0, 0);
        acc1 = __builtin_amdgcn_mfma_f32_16x16x32_f16(A1.v, B.v, acc1, 0, 0, 0);
    }

    // C/D: col j = n15, row m = q*4 + r. Fused attention dots (reduce over j).
    const float as = a_src2[n15], ad = a_dst2[n15];
#pragma unroll
    for (int m = 0; m < 2; ++m) {
        const f32x4 acc = m ? acc1 : acc0;
#pragma unroll
        for (int r = 0; r < 4; ++r) {
            const int node = n0 + m * 64 + q * 4 + r;
            float ps = acc[r] * as;
            float pd = acc[r] * ad;
#pragma unroll
            for (int o = 1; o < 16; o <<= 1) {
                ps += __shfl_xor(ps, o, 64);
                pd += __shfl_xor(pd, o, 64);
            }
            if (node < N_NODES) {
                xw2h[(size_t)node * 16 + n15] = __float2half(acc[r]);  // 32B runs/quad
                if (n15 == 0) { al2[node] = ps; ar2[node] = pd; }
            }
        }
    }
}

// ---------------------------------------------------------------------------
// Layer 2 pull-aggregation: one wave per node; 32 edges in flight — mean
// degree 17 completes in ONE memory round (xw2h 3.2MB ~L2-resident).
// ---------------------------------------------------------------------------
__global__ __launch_bounds__(256)
void k_aggr2(const int* __restrict__ ssrc, const int* __restrict__ offs,
             const int* __restrict__ deg, const float* __restrict__ al2,
             const float* __restrict__ ar2, const __half* __restrict__ xw2h,
             const float* __restrict__ b2, float* __restrict__ out) {
    const int lane = threadIdx.x & 63;
    const int node = blockIdx.x * 4 + (threadIdx.x >> 6);
    const int j2 = lane & 7;                 // feature pair 2*j2, 2*j2+1
    const int eL = lane >> 3;                // 0..7
    const int beg = offs[node];
    const int n = deg[node];
    const float ard = ar2[node];
    float a0 = 0.f, a1 = 0.f, dnm = 0.f;
    for (int base = 0; base < n; base += 32) {
#pragma unroll
        for (int u = 0; u < 4; ++u) {
            const int e = base + u * 8 + eL;
            const bool p = e < n;
            const int s = ssrc[beg + (p ? e : 0)];
            float v = al2[s] + ard;
            v = v > 0.f ? v : NEG_SLOPE * v;
            const float w = p ? __expf(v) : 0.f;
            const float2 f = __half22float2(*(const __half2*)&xw2h[(size_t)s * 16 + j2 * 2]);
            a0 = fmaf(w, f.x, a0);
            a1 = fmaf(w, f.y, a1);
            dnm += w;
        }
    }
#pragma unroll
    for (int o = 8; o < 64; o <<= 1) {
        a0 += __shfl_xor(a0, o, 64);
        a1 += __shfl_xor(a1, o, 64);
        dnm += __shfl_xor(dnm, o, 64);
    }
    if (eL == 0) {
        out[(size_t)node * 16 + j2 * 2]     = a0 / dnm + b2[j2 * 2];
        out[(size_t)node * 16 + j2 * 2 + 1] = a1 / dnm + b2[j2 * 2 + 1];
    }
}

extern "C" void kernel_launch(void* const* d_in, const int* in_sizes, int n_in,
                              void* d_out, int out_size, void* d_ws, size_t ws_size,
                              hipStream_t stream) {
    const float* x      = (const float*)d_in[0];
    const int*   ei     = (const int*)d_in[1];
    const float* W1     = (const float*)d_in[2];
    const float* a_src1 = (const float*)d_in[3];
    const float* a_dst1 = (const float*)d_in[4];
    const float* b1     = (const float*)d_in[5];
    const float* W2     = (const float*)d_in[6];
    const float* a_src2 = (const float*)d_in[7];
    const float* a_dst2 = (const float*)d_in[8];
    const float* b2     = (const float*)d_in[9];
    float* out = (float*)d_out;

    // Workspace (byte-addressed). Aliases:
    //  - pairs (8.4MB packed) sits in out1h's region: consumed by k_fill3
    //    before k_aggr1 writes out1h.
    //  - xw2h/al2/ar2 sit in xw1h's region: written by k_gemm2m after k_aggr1
    //    is done with xw1h.
    char* wsb = (char*)d_ws;
    __half* xw1h = (__half*)wsb;                                  // N*128 half (25.6 MB)
    __half* xw2h = (__half*)wsb;                                  // N*16 half (alias)
    float*  al2  = (float*)(wsb + (size_t)N_NODES * 16 * 2);      // N fp32 (alias)
    float*  ar2  = al2 + N_NODES;                                 // N fp32 (alias)
    __half* out1h = (__half*)(wsb + (size_t)N_NODES * 128 * 2);   // N*128 half (25.6 MB)
    int*    pairs = (int*)out1h;                                  // NBUCK*PBSTRIDE int (8.4 MB)
    float*  al1  = (float*)(wsb + (size_t)N_NODES * 128 * 4);     // N*4 fp32
    float*  ar1  = al1 + (size_t)N_NODES * 4;                     // N*4
    int* ibcnt = (int*)(ar1 + (size_t)N_NODES * 4);               // NBUCK (512 reserved)
    int* ioff  = ibcnt + 512;                                     // N
    int* ideg  = ioff + N_NODES;                                  // N
    int* isrc  = ideg + N_NODES;                                  // E_TOT

    hipMemsetAsync(ibcnt, 0, 512 * sizeof(int), stream);

    // Merged: MFMA layer-1 GEMM (staged-x, M=64) + edge bucket partition.
    k_gemm1_part<<<NGEMM + NPART, 256, 0, stream>>>(x, W1, a_src1, a_dst1,
                                                    ei, ibcnt, pairs, xw1h, al1, ar1);
    // Per-bucket counting sort -> CSR (ioff/ideg/isrc); 391 blocks (R7).
    k_fill3<<<NBUCK, 256, 0, stream>>>(pairs, ibcnt, ioff, ideg, isrc);

    // Layer 1 aggregation
    k_aggr1<<<N_NODES / 4, 256, 0, stream>>>(isrc, ioff, ideg, al1, ar1, xw1h, b1, out1h);

    // Layer 2 GEMM (MFMA, 2 M-tiles/wave) + fused attention dots
    k_gemm2m<<<(N_NODES + 127) / 128, 256, 0, stream>>>(out1h, W2, a_src2, a_dst2, xw2h, al2, ar2);

    // Layer 2 aggregation
    k_aggr2<<<N_NODES / 4, 256, 0, stream>>>(isrc, ioff, ideg, al2, ar2, xw2h, b2, out);
}